// Round 2
// baseline (4622.312 us; speedup 1.0000x reference)
//
#include <hip/hip_runtime.h>

#define SEQ  256
#define HID  64
#define FIN  5
#define BB   16
#define TPB  256
#define BTOT 4096

__device__ __forceinline__ float sigf(float x)   { return 1.0f / (1.0f + __expf(-x)); }
__device__ __forceinline__ float tanhf_(float x) { return 2.0f / (1.0f + __expf(-2.0f * x)) - 1.0f; }

// ws layout (floats): whh0p[64*256] | wih1p[64*256] | whh1p[64*256] | wih0p[5*256] | b0p[256] | b1p[256]
#define WS_WHH0 0
#define WS_WIH1 (64 * 256)
#define WS_WHH1 (2 * 64 * 256)
#define WS_WIH0 (3 * 64 * 256)
#define WS_B0   (3 * 64 * 256 + 5 * 256)
#define WS_B1   (WS_B0 + 256)
#define WS_TOT  (WS_B1 + 256)

// Permute weights to gate-interleaved layout: Wp[k][4*j+g] = W[g*64+j][k].
// Thread j then reads a contiguous float4 = (i,f,g,o) weights of hidden unit j.
__global__ void prep_kernel(const float* __restrict__ wih0, const float* __restrict__ whh0,
                            const float* __restrict__ bih0, const float* __restrict__ bhh0,
                            const float* __restrict__ wih1, const float* __restrict__ whh1,
                            const float* __restrict__ bih1, const float* __restrict__ bhh1,
                            float* __restrict__ ws) {
    int idx = blockIdx.x * blockDim.x + threadIdx.x;
    if (idx < 64 * 256) {
        int k = idx >> 8, c = idx & 255;
        int j = c >> 2, g = c & 3;
        int row = g * 64 + j;
        ws[WS_WHH0 + idx] = whh0[row * 64 + k];
        ws[WS_WIH1 + idx] = wih1[row * 64 + k];
        ws[WS_WHH1 + idx] = whh1[row * 64 + k];
    }
    if (idx < FIN * 256) {
        int f = idx >> 8, c = idx & 255;
        int j = c >> 2, g = c & 3;
        ws[WS_WIH0 + idx] = wih0[(g * 64 + j) * FIN + f];
    }
    if (idx < 256) {
        int j = idx >> 2, g = idx & 3;
        int row = g * 64 + j;
        ws[WS_B0 + idx] = bih0[row] + bhh0[row];
        ws[WS_B1 + idx] = bih1[row] + bhh1[row];
    }
}

#define FMA4(acc, w, s) { acc.x += w.x * (s); acc.y += w.y * (s); acc.z += w.z * (s); acc.w += w.w * (s); }
#define UPD1(acc, ci, hv) { float iv = sigf(acc.x), fv = sigf(acc.y), gv = tanhf_(acc.z), ov = sigf(acc.w); \
                            ci = fv * ci + iv * gv; hv = ov * tanhf_(ci); }

__global__ __launch_bounds__(TPB, 1)
void lstm_fused_kernel(const float* __restrict__ x, const float* __restrict__ ws,
                       const float* __restrict__ ew1, const float* __restrict__ eb1,
                       const float* __restrict__ ew2, const float* __restrict__ eb2,
                       const float* __restrict__ pw1, const float* __restrict__ pb1,
                       const float* __restrict__ pw2, const float* __restrict__ pb2,
                       const float* __restrict__ sw,  const float* __restrict__ sb,
                       float* __restrict__ out) {
    __shared__ float V0[HID][20];      // h1 state, padded rows (80 B, 16B-aligned)
    __shared__ float V1[HID][20];      // h2 state
    __shared__ float XB[FIN][20];      // x_t staging
    __shared__ float HS[2][BB][17];    // head hidden activations

    const int tid = threadIdx.x;
    const int j   = tid >> 2;   // hidden unit 0..63
    const int q   = tid & 3;    // batch quad 0..3 (batches 4q..4q+3)
    const int b0g = blockIdx.x * BB;

    const float4* W0  = (const float4*)(ws + WS_WHH0);  // [k*64 + j]
    const float4* W1a = (const float4*)(ws + WS_WHH1);
    const float4* W1b = (const float4*)(ws + WS_WIH1);

    for (int i = tid; i < HID * 20; i += TPB) { (&V0[0][0])[i] = 0.0f; (&V1[0][0])[i] = 0.0f; }
    if (tid < BB * FIN) {
        int b = tid / FIN, f = tid % FIN;
        XB[f][b] = x[(size_t)(b0g + b) * (SEQ * FIN) + f];
    }

    const float4 bias0 = *(const float4*)(ws + WS_B0 + 4 * j);
    const float4 bias1 = *(const float4*)(ws + WS_B1 + 4 * j);
    float4 wi0[FIN];
    #pragma unroll
    for (int f = 0; f < FIN; ++f) wi0[f] = *(const float4*)(ws + WS_WIH0 + f * 256 + 4 * j);

    float c1_0 = 0.f, c1_1 = 0.f, c1_2 = 0.f, c1_3 = 0.f;
    float c2_0 = 0.f, c2_1 = 0.f, c2_2 = 0.f, c2_3 = 0.f;

    __syncthreads();

    for (int t = 0; t < SEQ; ++t) {
        // ---------------- layer 0 GEMM: gates(j; 4 batches) ----------------
        float4 a0 = bias0, a1 = bias0, a2 = bias0, a3 = bias0;
        #pragma unroll
        for (int f = 0; f < FIN; ++f) {
            float4 v = *(const float4*)&XB[f][q * 4];
            float4 w = wi0[f];
            FMA4(a0, w, v.x); FMA4(a1, w, v.y); FMA4(a2, w, v.z); FMA4(a3, w, v.w);
        }
        #pragma unroll 8
        for (int k = 0; k < HID; ++k) {
            float4 w = W0[k * 64 + j];                    // L2-streamed weights
            float4 v = *(const float4*)&V0[k][q * 4];     // LDS broadcast
            FMA4(a0, w, v.x); FMA4(a1, w, v.y); FMA4(a2, w, v.z); FMA4(a3, w, v.w);
        }
        __syncthreads();  // B1: all V0/XB reads of step t done

        // ---------------- layer 0 pointwise update (registers) -------------
        float h0, h1v, h2v, h3v;
        UPD1(a0, c1_0, h0); UPD1(a1, c1_1, h1v); UPD1(a2, c1_2, h2v); UPD1(a3, c1_3, h3v);
        *(float4*)&V0[j][q * 4] = make_float4(h0, h1v, h2v, h3v);
        if (t + 1 < SEQ && tid < BB * FIN) {
            int b = tid / FIN, f = tid % FIN;
            XB[f][b] = x[(size_t)(b0g + b) * (SEQ * FIN) + (t + 1) * FIN + f];
        }
        __syncthreads();  // B2: V0 now holds h1_t

        // ---------------- layer 1 GEMM -------------------------------------
        float4 d0 = bias1, d1 = bias1, d2 = bias1, d3 = bias1;
        #pragma unroll 8
        for (int k = 0; k < HID; ++k) {
            float4 w = W1a[k * 64 + j];                   // w_hh1 (recurrent)
            float4 v = *(const float4*)&V1[k][q * 4];     // h2_{t-1}
            FMA4(d0, w, v.x); FMA4(d1, w, v.y); FMA4(d2, w, v.z); FMA4(d3, w, v.w);
        }
        #pragma unroll 8
        for (int k = 0; k < HID; ++k) {
            float4 w = W1b[k * 64 + j];                   // w_ih1 (input)
            float4 v = *(const float4*)&V0[k][q * 4];     // h1_t
            FMA4(d0, w, v.x); FMA4(d1, w, v.y); FMA4(d2, w, v.z); FMA4(d3, w, v.w);
        }
        __syncthreads();  // B3: all V1 reads of step t done

        // ---------------- layer 1 pointwise update -------------------------
        float g0, g1, g2, g3;
        UPD1(d0, c2_0, g0); UPD1(d1, c2_1, g1); UPD1(d2, c2_2, g2); UPD1(d3, c2_3, g3);
        *(float4*)&V1[j][q * 4] = make_float4(g0, g1, g2, g3);
        __syncthreads();  // B4: V1 holds h2_t
    }

    // ---------------- heads (one-time epilogue) ----------------------------
    {
        int b = tid >> 4, i = tid & 15;   // 16 batches x 16 hidden
        float ae = eb1[i], ap = pb1[i];
        for (int jj = 0; jj < HID; ++jj) {
            float h = V1[jj][b];
            ae += h * ew1[i * HID + jj];
            ap += h * pw1[i * HID + jj];
        }
        HS[0][b][i] = fmaxf(ae, 0.0f);
        HS[1][b][i] = fmaxf(ap, 0.0f);
    }
    __syncthreads();
    if (tid < BB) {
        float eo = eb2[0], po = pb2[0];
        #pragma unroll
        for (int i2 = 0; i2 < 16; ++i2) {
            eo += HS[0][tid][i2] * ew2[i2];
            po += HS[1][tid][i2] * pw2[i2];
        }
        out[b0g + tid]        = sigf(eo);
        out[BTOT + b0g + tid] = sigf(po);
    }
    if (tid < BB * 5) {
        int b = tid / 5, s = tid % 5;
        float a = sb[s];
        for (int jj = 0; jj < HID; ++jj) a += V1[jj][b] * sw[s * HID + jj];
        out[2 * BTOT + (size_t)(b0g + b) * 5 + s] = a;
    }
}

extern "C" void kernel_launch(void* const* d_in, const int* in_sizes, int n_in,
                              void* d_out, int out_size, void* d_ws, size_t ws_size,
                              hipStream_t stream) {
    const float* x     = (const float*)d_in[0];
    const float* w_ih0 = (const float*)d_in[1];
    const float* w_hh0 = (const float*)d_in[2];
    const float* b_ih0 = (const float*)d_in[3];
    const float* b_hh0 = (const float*)d_in[4];
    const float* w_ih1 = (const float*)d_in[5];
    const float* w_hh1 = (const float*)d_in[6];
    const float* b_ih1 = (const float*)d_in[7];
    const float* b_hh1 = (const float*)d_in[8];
    const float* ew1 = (const float*)d_in[9];
    const float* eb1 = (const float*)d_in[10];
    const float* ew2 = (const float*)d_in[11];
    const float* eb2 = (const float*)d_in[12];
    const float* pw1 = (const float*)d_in[13];
    const float* pb1 = (const float*)d_in[14];
    const float* pw2 = (const float*)d_in[15];
    const float* pb2 = (const float*)d_in[16];
    const float* sw  = (const float*)d_in[17];
    const float* sb  = (const float*)d_in[18];
    float* out = (float*)d_out;
    float* ws  = (float*)d_ws;   // uses only WS_TOT*4 ≈ 200 KB

    hipLaunchKernelGGL(prep_kernel, dim3(64), dim3(256), 0, stream,
                       w_ih0, w_hh0, b_ih0, b_hh0, w_ih1, w_hh1, b_ih1, b_hh1, ws);
    hipLaunchKernelGGL(lstm_fused_kernel, dim3(BTOT / BB), dim3(TPB), 0, stream,
                       x, ws, ew1, eb1, ew2, eb2, pw1, pb1, pw2, pb2, sw, sb, out);
}

// Round 3
// 2227.707 us; speedup vs baseline: 2.0749x; 2.0749x over previous
//
#include <hip/hip_runtime.h>

#define SEQ  256
#define HID  64
#define FIN  5
#define G4   256   // 4*HID gate columns
#define BB   16    // batch rows per block
#define TPB  512
#define BTOT 4096

__device__ __forceinline__ float sigf(float x)   { return 1.0f / (1.0f + __expf(-x)); }
__device__ __forceinline__ float tanhf_(float x) { return 2.0f / (1.0f + __expf(-2.0f * x)) - 1.0f; }

// ws layout (floats): whh0p[64*256] | wih1p[64*256] | whh1p[64*256] | wih0p[5*256] | b0p[256] | b1p[256]
#define WS_WHH0 0
#define WS_WIH1 (64 * 256)
#define WS_WHH1 (2 * 64 * 256)
#define WS_WIH0 (3 * 64 * 256)
#define WS_B0   (3 * 64 * 256 + 5 * 256)
#define WS_B1   (WS_B0 + 256)

// Gate-interleaved permutation: Wp[k][4*j+g] = W[g*64+j][k], so thread j reads
// one contiguous float4 = (i,f,g,o) weights of hidden unit j at row k.
__global__ void prep_kernel(const float* __restrict__ wih0, const float* __restrict__ whh0,
                            const float* __restrict__ bih0, const float* __restrict__ bhh0,
                            const float* __restrict__ wih1, const float* __restrict__ whh1,
                            const float* __restrict__ bih1, const float* __restrict__ bhh1,
                            float* __restrict__ ws) {
    int idx = blockIdx.x * blockDim.x + threadIdx.x;
    if (idx < 64 * 256) {
        int k = idx >> 8, c = idx & 255;
        int j = c >> 2, g = c & 3;
        int row = g * 64 + j;
        ws[WS_WHH0 + idx] = whh0[row * 64 + k];
        ws[WS_WIH1 + idx] = wih1[row * 64 + k];
        ws[WS_WHH1 + idx] = whh1[row * 64 + k];
    }
    if (idx < FIN * 256) {
        int f = idx >> 8, c = idx & 255;
        int j = c >> 2, g = c & 3;
        ws[WS_WIH0 + idx] = wih0[(g * 64 + j) * FIN + f];
    }
    if (idx < 256) {
        int j = idx >> 2, g = idx & 3;
        int row = g * 64 + j;
        ws[WS_B0 + idx] = bih0[row] + bhh0[row];
        ws[WS_B1 + idx] = bih1[row] + bhh1[row];
    }
}

#define FMA4(acc, w, s) { acc.x += w.x * (s); acc.y += w.y * (s); acc.z += w.z * (s); acc.w += w.w * (s); }
#define UPD1(acc, ci, hv) { float iv = sigf(acc.x), fv = sigf(acc.y), gv = tanhf_(acc.z), ov = sigf(acc.w); \
                            ci = fv * ci + iv * gv; hv = ov * tanhf_(ci); }

// One block = 16 batch rows, 512 threads = 64 hidden-units x 8 batch-pairs.
// w_hh0 & w_hh1 live in LDS (staged once); w_ih1 streams from L2 (64KB/step,
// coalesces to 128B per wave per k). Double-buffered h-state -> 2 barriers/step.
__global__ __launch_bounds__(TPB, 2)
void lstm_fused_kernel(const float* __restrict__ x, const float* __restrict__ ws,
                       const float* __restrict__ ew1, const float* __restrict__ eb1,
                       const float* __restrict__ ew2, const float* __restrict__ eb2,
                       const float* __restrict__ pw1, const float* __restrict__ pb1,
                       const float* __restrict__ pw2, const float* __restrict__ pb2,
                       const float* __restrict__ sw,  const float* __restrict__ sb,
                       float* __restrict__ out) {
    __shared__ float W0s[HID][G4];        // whh0 permuted, 64 KB
    __shared__ float W1s[HID][G4];        // whh1 permuted, 64 KB
    __shared__ float V0[2][HID][20];      // h1 state, double-buffered, padded rows
    __shared__ float V1[2][HID][20];      // h2 state
    __shared__ float XB[2][FIN][20];      // x_t staging
    __shared__ float HS[2][BB][17];       // head hidden activations

    const int tid = threadIdx.x;
    const int j   = tid >> 3;   // hidden unit 0..63
    const int q   = tid & 7;    // batch pair 0..7 (batches 2q, 2q+1)
    const int b0g = blockIdx.x * BB;

    // ---- stage recurrent weights into LDS (once) ----
    {
        const float4* s0 = (const float4*)(ws + WS_WHH0);
        const float4* s1 = (const float4*)(ws + WS_WHH1);
        float4* d0 = (float4*)&W0s[0][0];
        float4* d1 = (float4*)&W1s[0][0];
        for (int i = tid; i < HID * G4 / 4; i += TPB) { d0[i] = s0[i]; d1[i] = s1[i]; }
    }
    for (int i = tid; i < 2 * HID * 20; i += TPB) {
        (&V0[0][0][0])[i] = 0.0f; (&V1[0][0][0])[i] = 0.0f;
    }
    if (tid < BB * FIN) {
        int b = tid / FIN, f = tid % FIN;
        XB[0][f][b] = x[(size_t)(b0g + b) * (SEQ * FIN) + f];
    }

    const float4 bias0 = *(const float4*)(ws + WS_B0 + 4 * j);
    const float4 bias1 = *(const float4*)(ws + WS_B1 + 4 * j);
    float4 wi0[FIN];
    #pragma unroll
    for (int f = 0; f < FIN; ++f) wi0[f] = *(const float4*)(ws + WS_WIH0 + f * 256 + 4 * j);
    const float4* W1b = (const float4*)(ws + WS_WIH1);   // [k*64 + j], L2-resident

    float c10 = 0.f, c11 = 0.f, c20 = 0.f, c21 = 0.f;

    __syncthreads();

    for (int t = 0; t < SEQ; ++t) {
        const int cur = t & 1, nxt = cur ^ 1;

        // ---------------- layer 0 GEMM (reads V0[cur], XB[cur]) ------------
        float4 a0 = bias0, a1 = bias0;
        #pragma unroll
        for (int f = 0; f < FIN; ++f) {
            float2 v = *(const float2*)&XB[cur][f][2 * q];
            float4 w = wi0[f];
            FMA4(a0, w, v.x); FMA4(a1, w, v.y);
        }
        #pragma unroll 8
        for (int k = 0; k < HID; ++k) {
            float4 w = *(const float4*)&W0s[k][4 * j];
            float2 v = *(const float2*)&V0[cur][k][2 * q];
            FMA4(a0, w, v.x); FMA4(a1, w, v.y);
        }

        // ---------------- layer 0 pointwise -> V0[nxt] ----------------------
        float h0, h1v;
        UPD1(a0, c10, h0); UPD1(a1, c11, h1v);
        *(float2*)&V0[nxt][j][2 * q] = make_float2(h0, h1v);
        if (t + 1 < SEQ && tid < BB * FIN) {
            int b = tid / FIN, f = tid % FIN;
            XB[nxt][f][b] = x[(size_t)(b0g + b) * (SEQ * FIN) + (t + 1) * FIN + f];
        }
        __syncthreads();   // V0[nxt]=h1_t visible; all V0[cur]/XB[cur] reads done

        // ---------------- layer 1 GEMM (reads V1[cur], V0[nxt]) ------------
        float4 d0 = bias1, d1 = bias1;
        #pragma unroll 8
        for (int k = 0; k < HID; ++k) {
            float4 w = *(const float4*)&W1s[k][4 * j];
            float2 v = *(const float2*)&V1[cur][k][2 * q];
            FMA4(d0, w, v.x); FMA4(d1, w, v.y);
        }
        #pragma unroll 8
        for (int k = 0; k < HID; ++k) {
            float4 w = W1b[k * 64 + j];                      // L2 stream
            float2 v = *(const float2*)&V0[nxt][k][2 * q];
            FMA4(d0, w, v.x); FMA4(d1, w, v.y);
        }

        // ---------------- layer 1 pointwise -> V1[nxt] ----------------------
        float g0, g1;
        UPD1(d0, c20, g0); UPD1(d1, c21, g1);
        *(float2*)&V1[nxt][j][2 * q] = make_float2(g0, g1);
        __syncthreads();   // V1[nxt]=h2_t visible; V1[cur] reads done
    }

    // ---------------- heads (final h2 is in V1[0]; SEQ even) ---------------
    if (tid < 256) {
        int b = tid >> 4, i = tid & 15;
        float ae = eb1[i], ap = pb1[i];
        for (int jj = 0; jj < HID; ++jj) {
            float h = V1[0][jj][b];
            ae += h * ew1[i * HID + jj];
            ap += h * pw1[i * HID + jj];
        }
        HS[0][b][i] = fmaxf(ae, 0.0f);
        HS[1][b][i] = fmaxf(ap, 0.0f);
    }
    __syncthreads();
    if (tid < BB) {
        float eo = eb2[0], po = pb2[0];
        #pragma unroll
        for (int i2 = 0; i2 < 16; ++i2) {
            eo += HS[0][tid][i2] * ew2[i2];
            po += HS[1][tid][i2] * pw2[i2];
        }
        out[b0g + tid]        = sigf(eo);
        out[BTOT + b0g + tid] = sigf(po);
    }
    if (tid < BB * 5) {
        int b = tid / 5, s = tid % 5;
        float a = sb[s];
        for (int jj = 0; jj < HID; ++jj) a += V1[0][jj][b] * sw[s * HID + jj];
        out[2 * BTOT + (size_t)(b0g + b) * 5 + s] = a;
    }
}

extern "C" void kernel_launch(void* const* d_in, const int* in_sizes, int n_in,
                              void* d_out, int out_size, void* d_ws, size_t ws_size,
                              hipStream_t stream) {
    const float* x     = (const float*)d_in[0];
    const float* w_ih0 = (const float*)d_in[1];
    const float* w_hh0 = (const float*)d_in[2];
    const float* b_ih0 = (const float*)d_in[3];
    const float* b_hh0 = (const float*)d_in[4];
    const float* w_ih1 = (const float*)d_in[5];
    const float* w_hh1 = (const float*)d_in[6];
    const float* b_ih1 = (const float*)d_in[7];
    const float* b_hh1 = (const float*)d_in[8];
    const float* ew1 = (const float*)d_in[9];
    const float* eb1 = (const float*)d_in[10];
    const float* ew2 = (const float*)d_in[11];
    const float* eb2 = (const float*)d_in[12];
    const float* pw1 = (const float*)d_in[13];
    const float* pb1 = (const float*)d_in[14];
    const float* pw2 = (const float*)d_in[15];
    const float* pb2 = (const float*)d_in[16];
    const float* sw  = (const float*)d_in[17];
    const float* sb  = (const float*)d_in[18];
    float* out = (float*)d_out;
    float* ws  = (float*)d_ws;   // ~200 KB used

    hipLaunchKernelGGL(prep_kernel, dim3(64), dim3(256), 0, stream,
                       w_ih0, w_hh0, b_ih0, b_hh0, w_ih1, w_hh1, b_ih1, b_hh1, ws);
    hipLaunchKernelGGL(lstm_fused_kernel, dim3(BTOT / BB), dim3(TPB), 0, stream,
                       x, ws, ew1, eb1, ew2, eb2, pw1, pb1, pw2, pb2, sw, sb, out);
}

// Round 4
// 561.638 us; speedup vs baseline: 8.2301x; 3.9664x over previous
//
#include <hip/hip_runtime.h>

typedef __attribute__((ext_vector_type(8))) short short8_t;
typedef __attribute__((ext_vector_type(4))) float f32x4;

#define SEQ  256
#define HID  64
#define FIN  5
#define BB   16
#define TPB  512
#define BTOT 4096

// ws byte offsets: fragged bf16 weights (hi/lo) + fp32 wih0/biases
#define OFF_W0HI 0
#define OFF_W0LO (32*1024)
#define OFF_W1HI (64*1024)
#define OFF_W1LO (96*1024)
#define OFF_W2HI (128*1024)
#define OFF_W2LO (160*1024)
#define OFF_WIH0 (192*1024)            // 1280 f32: wih0p[c][f]
#define OFF_B0   (192*1024 + 5120)     // 256 f32
#define OFF_B1   (192*1024 + 6144)     // 256 f32

__device__ __forceinline__ float sigf(float v)   { return 1.0f / (1.0f + __expf(-v)); }
__device__ __forceinline__ float tanhf_(float v) { return 2.0f / (1.0f + __expf(-2.0f*v)) - 1.0f; }

// ---------------------------------------------------------------------------
// Prep: split each weight matrix (gate-interleaved cols c=4J+g) into bf16
// hi/lo and lay it out pre-fragged for mfma_16x16x32: element order
// e = ((T*2+ks)*64 + lane)*8 + i  with  c = 16T + (lane&15),
// k = ks*32 + (lane>>4)*8 + i   (A-frag: row=lane&15, k=(lane>>4)*8+i).
// ---------------------------------------------------------------------------
__global__ void prep_kernel(const float* __restrict__ wih0, const float* __restrict__ whh0,
                            const float* __restrict__ bih0, const float* __restrict__ bhh0,
                            const float* __restrict__ wih1, const float* __restrict__ whh1,
                            const float* __restrict__ bih1, const float* __restrict__ bhh1,
                            unsigned char* __restrict__ ws) {
    int idx = blockIdx.x * blockDim.x + threadIdx.x;
    if (idx < 3 * 16384) {
        int mat = idx / 16384, e = idx % 16384;
        int tk   = e >> 9;           // T*2+ks, 0..31
        int lane = (e >> 3) & 63;
        int i    = e & 7;
        int c = 16 * (tk >> 1) + (lane & 15);
        int k = (tk & 1) * 32 + (lane >> 4) * 8 + i;
        int row = (c & 3) * 64 + (c >> 2);      // PyTorch row = gate*64 + J
        const float* W = (mat == 0) ? whh0 : (mat == 1) ? whh1 : wih1;
        float v = W[row * HID + k];
        unsigned int vb = __float_as_uint(v);
        unsigned short hi = (unsigned short)(vb >> 16);
        float rem = v - __uint_as_float(vb & 0xffff0000u);
        unsigned short lo = (unsigned short)(__float_as_uint(rem) >> 16);
        int bhiOff = (mat == 0) ? OFF_W0HI : (mat == 1) ? OFF_W1HI : OFF_W2HI;
        int bloOff = (mat == 0) ? OFF_W0LO : (mat == 1) ? OFF_W1LO : OFF_W2LO;
        ((unsigned short*)(ws + bhiOff))[e] = hi;
        ((unsigned short*)(ws + bloOff))[e] = lo;
    }
    if (idx < 1280) {
        int c = idx / FIN, f = idx % FIN;
        int row = (c & 3) * 64 + (c >> 2);
        ((float*)(ws + OFF_WIH0))[idx] = wih0[row * FIN + f];
    }
    if (idx < 256) {
        int row = (idx & 3) * 64 + (idx >> 2);
        ((float*)(ws + OFF_B0))[idx] = bih0[row] + bhh0[row];
        ((float*)(ws + OFF_B1))[idx] = bih1[row] + bhh1[row];
    }
}

// pointwise update + packed bf16(hi,lo) state write; pairs J,J^1 via swizzle xor16
#define UPDW(acc, cs, Tl, VH, VL, buf) {                                          \
    float iv = sigf(acc[0]), fv = sigf(acc[1]);                                   \
    float gv = tanhf_(acc[2]), ov = sigf(acc[3]);                                 \
    cs = fv * cs + iv * gv;                                                       \
    float hv = ov * tanhf_(cs);                                                   \
    unsigned int hb  = __float_as_uint(hv);                                       \
    unsigned int hi16 = hb & 0xffff0000u;                                         \
    float rem = hv - __uint_as_float(hi16);                                       \
    unsigned int lo16 = __float_as_uint(rem) & 0xffff0000u;                       \
    unsigned int phi = (unsigned int)__builtin_amdgcn_ds_swizzle((int)hi16, 0x401F); \
    unsigned int plo = (unsigned int)__builtin_amdgcn_ds_swizzle((int)lo16, 0x401F); \
    if ((g & 1) == 0) {                                                           \
        int jp = 2 * (2 * w + Tl) + (g >> 1);                                     \
        VH[buf][b][jp] = (hi16 >> 16) | (phi & 0xffff0000u);                      \
        VL[buf][b][jp] = (lo16 >> 16) | (plo & 0xffff0000u);                      \
    } }

__global__ __launch_bounds__(TPB, 2)
void lstm_fused_kernel(const float* __restrict__ x, const unsigned char* __restrict__ ws,
                       const float* __restrict__ ew1, const float* __restrict__ eb1,
                       const float* __restrict__ ew2, const float* __restrict__ eb2,
                       const float* __restrict__ pw1, const float* __restrict__ pb1,
                       const float* __restrict__ pw2, const float* __restrict__ pb2,
                       const float* __restrict__ sw,  const float* __restrict__ sb,
                       float* __restrict__ out) {
    // h-states as packed u32 = (bf16 lo of h[2Jp] | bf16 hi... low16=J even, high16=J odd)
    __shared__ unsigned int Vhi0[2][16][36], Vlo0[2][16][36];
    __shared__ unsigned int Vhi1[2][16][36], Vlo1[2][16][36];
    __shared__ float XB[2][16][9];
    __shared__ float HS[2][16][17];

    const int tid  = threadIdx.x;
    const int lane = tid & 63;
    const int w    = tid >> 6;      // wave 0..7 -> tiles 2w, 2w+1
    const int b    = lane & 15;     // batch (B-frag col / D col)
    const int g    = lane >> 4;     // k-chunk id / D row-quad id
    const int b0g  = blockIdx.x * BB;

    // ---- zero-init states, stage x(t=0) ----
    for (int i = tid; i < 2 * 16 * 36; i += TPB) {
        (&Vhi0[0][0][0])[i] = 0u; (&Vlo0[0][0][0])[i] = 0u;
        (&Vhi1[0][0][0])[i] = 0u; (&Vlo1[0][0][0])[i] = 0u;
    }
    const int xb_ = tid / FIN, xf_ = tid % FIN;   // valid for tid<80
    if (tid < BB * FIN)
        XB[0][xb_][xf_] = x[(size_t)(b0g + xb_) * (SEQ * FIN) + xf_];

    // ---- weight fragments -> VGPRs (once) ----
    short8_t A0h[2][2], A0l[2][2], A1h[2][2], A1l[2][2], A2h[2][2], A2l[2][2];
    #pragma unroll
    for (int Tl = 0; Tl < 2; ++Tl)
        #pragma unroll
        for (int ks = 0; ks < 2; ++ks) {
            int fo = (((2 * w + Tl) * 2 + ks) * 64 + lane) * 16;
            A0h[Tl][ks] = *(const short8_t*)(ws + OFF_W0HI + fo);
            A0l[Tl][ks] = *(const short8_t*)(ws + OFF_W0LO + fo);
            A1h[Tl][ks] = *(const short8_t*)(ws + OFF_W1HI + fo);
            A1l[Tl][ks] = *(const short8_t*)(ws + OFF_W1LO + fo);
            A2h[Tl][ks] = *(const short8_t*)(ws + OFF_W2HI + fo);
            A2l[Tl][ks] = *(const short8_t*)(ws + OFF_W2LO + fo);
        }
    float bias0r[2][4], bias1r[2][4], wir[2][4][5];
    #pragma unroll
    for (int Tl = 0; Tl < 2; ++Tl)
        #pragma unroll
        for (int r = 0; r < 4; ++r) {
            int c = 16 * (2 * w + Tl) + 4 * g + r;
            bias0r[Tl][r] = ((const float*)(ws + OFF_B0))[c];
            bias1r[Tl][r] = ((const float*)(ws + OFF_B1))[c];
            #pragma unroll
            for (int f = 0; f < FIN; ++f)
                wir[Tl][r][f] = ((const float*)(ws + OFF_WIH0))[c * FIN + f];
        }

    float c1[2] = {0.f, 0.f}, c2[2] = {0.f, 0.f};
    float xnext = 0.f;

    __syncthreads();

    for (int t = 0; t < SEQ; ++t) {
        const int cur = t & 1, nxt = cur ^ 1;
        if (tid < BB * FIN && t + 1 < SEQ)
            xnext = x[(size_t)(b0g + xb_) * (SEQ * FIN) + (t + 1) * FIN + xf_];

        // ---------- layer 0: acc = bias + x*wih0 (exact fp32) ----------
        f32x4 acc0, acc1;
        float xv[5];
        #pragma unroll
        for (int f = 0; f < FIN; ++f) xv[f] = XB[cur][b][f];
        #pragma unroll
        for (int r = 0; r < 4; ++r) {
            float a0 = bias0r[0][r], a1 = bias0r[1][r];
            #pragma unroll
            for (int f = 0; f < FIN; ++f) { a0 += xv[f] * wir[0][r][f]; a1 += xv[f] * wir[1][r][f]; }
            acc0[r] = a0; acc1[r] = a1;
        }
        // ---------- layer 0 MFMAs: h1prev (bf16x3) ----------
        #pragma unroll
        for (int ks = 0; ks < 2; ++ks) {
            short8_t bh = *(const short8_t*)&Vhi0[cur][b][16 * ks + 4 * g];
            short8_t bl = *(const short8_t*)&Vlo0[cur][b][16 * ks + 4 * g];
            acc0 = __builtin_amdgcn_mfma_f32_16x16x32_bf16(A0h[0][ks], bh, acc0, 0, 0, 0);
            acc1 = __builtin_amdgcn_mfma_f32_16x16x32_bf16(A0h[1][ks], bh, acc1, 0, 0, 0);
            acc0 = __builtin_amdgcn_mfma_f32_16x16x32_bf16(A0h[0][ks], bl, acc0, 0, 0, 0);
            acc1 = __builtin_amdgcn_mfma_f32_16x16x32_bf16(A0h[1][ks], bl, acc1, 0, 0, 0);
            acc0 = __builtin_amdgcn_mfma_f32_16x16x32_bf16(A0l[0][ks], bh, acc0, 0, 0, 0);
            acc1 = __builtin_amdgcn_mfma_f32_16x16x32_bf16(A0l[1][ks], bh, acc1, 0, 0, 0);
        }
        UPDW(acc0, c1[0], 0, Vhi0, Vlo0, nxt)
        UPDW(acc1, c1[1], 1, Vhi0, Vlo0, nxt)
        __syncthreads();   // h1_t visible

        // ---------- layer 1 ----------
        f32x4 d0, d1;
        #pragma unroll
        for (int r = 0; r < 4; ++r) { d0[r] = bias1r[0][r]; d1[r] = bias1r[1][r]; }
        #pragma unroll
        for (int ks = 0; ks < 2; ++ks) {          // recurrent: h2prev
            short8_t bh = *(const short8_t*)&Vhi1[cur][b][16 * ks + 4 * g];
            short8_t bl = *(const short8_t*)&Vlo1[cur][b][16 * ks + 4 * g];
            d0 = __builtin_amdgcn_mfma_f32_16x16x32_bf16(A1h[0][ks], bh, d0, 0, 0, 0);
            d1 = __builtin_amdgcn_mfma_f32_16x16x32_bf16(A1h[1][ks], bh, d1, 0, 0, 0);
            d0 = __builtin_amdgcn_mfma_f32_16x16x32_bf16(A1h[0][ks], bl, d0, 0, 0, 0);
            d1 = __builtin_amdgcn_mfma_f32_16x16x32_bf16(A1h[1][ks], bl, d1, 0, 0, 0);
            d0 = __builtin_amdgcn_mfma_f32_16x16x32_bf16(A1l[0][ks], bh, d0, 0, 0, 0);
            d1 = __builtin_amdgcn_mfma_f32_16x16x32_bf16(A1l[1][ks], bh, d1, 0, 0, 0);
        }
        #pragma unroll
        for (int ks = 0; ks < 2; ++ks) {          // input half: h1cur
            short8_t bh = *(const short8_t*)&Vhi0[nxt][b][16 * ks + 4 * g];
            short8_t bl = *(const short8_t*)&Vlo0[nxt][b][16 * ks + 4 * g];
            d0 = __builtin_amdgcn_mfma_f32_16x16x32_bf16(A2h[0][ks], bh, d0, 0, 0, 0);
            d1 = __builtin_amdgcn_mfma_f32_16x16x32_bf16(A2h[1][ks], bh, d1, 0, 0, 0);
            d0 = __builtin_amdgcn_mfma_f32_16x16x32_bf16(A2h[0][ks], bl, d0, 0, 0, 0);
            d1 = __builtin_amdgcn_mfma_f32_16x16x32_bf16(A2h[1][ks], bl, d1, 0, 0, 0);
            d0 = __builtin_amdgcn_mfma_f32_16x16x32_bf16(A2l[0][ks], bh, d0, 0, 0, 0);
            d1 = __builtin_amdgcn_mfma_f32_16x16x32_bf16(A2l[1][ks], bh, d1, 0, 0, 0);
        }
        UPDW(d0, c2[0], 0, Vhi1, Vlo1, nxt)
        UPDW(d1, c2[1], 1, Vhi1, Vlo1, nxt)
        if (tid < BB * FIN && t + 1 < SEQ)
            XB[nxt][xb_][xf_] = xnext;
        __syncthreads();   // h2_t visible
    }

    // ---------------- heads: final h2 is in buffer 0 ----------------
    if (tid < 256) {
        int hb_ = tid >> 4, hi_ = tid & 15;
        float ae = eb1[hi_], ap = pb1[hi_];
        for (int jp = 0; jp < 32; ++jp) {
            unsigned int uh = Vhi1[0][hb_][jp], ul = Vlo1[0][hb_][jp];
            float h0 = __uint_as_float(uh << 16) + __uint_as_float(ul << 16);
            float h1 = __uint_as_float(uh & 0xffff0000u) + __uint_as_float(ul & 0xffff0000u);
            ae += h0 * ew1[hi_ * HID + 2 * jp] + h1 * ew1[hi_ * HID + 2 * jp + 1];
            ap += h0 * pw1[hi_ * HID + 2 * jp] + h1 * pw1[hi_ * HID + 2 * jp + 1];
        }
        HS[0][hb_][hi_] = fmaxf(ae, 0.0f);
        HS[1][hb_][hi_] = fmaxf(ap, 0.0f);
    }
    if (tid < 80) {
        int sbb = tid / 5, ss = tid % 5;
        float a = sb[ss];
        for (int jp = 0; jp < 32; ++jp) {
            unsigned int uh = Vhi1[0][sbb][jp], ul = Vlo1[0][sbb][jp];
            float h0 = __uint_as_float(uh << 16) + __uint_as_float(ul << 16);
            float h1 = __uint_as_float(uh & 0xffff0000u) + __uint_as_float(ul & 0xffff0000u);
            a += h0 * sw[ss * HID + 2 * jp] + h1 * sw[ss * HID + 2 * jp + 1];
        }
        out[2 * BTOT + (size_t)(b0g + sbb) * 5 + ss] = a;
    }
    __syncthreads();
    if (tid < BB) {
        float eo = eb2[0], po = pb2[0];
        #pragma unroll
        for (int i2 = 0; i2 < 16; ++i2) {
            eo += HS[0][tid][i2] * ew2[i2];
            po += HS[1][tid][i2] * pw2[i2];
        }
        out[b0g + tid]        = sigf(eo);
        out[BTOT + b0g + tid] = sigf(po);
    }
}

extern "C" void kernel_launch(void* const* d_in, const int* in_sizes, int n_in,
                              void* d_out, int out_size, void* d_ws, size_t ws_size,
                              hipStream_t stream) {
    const float* x     = (const float*)d_in[0];
    const float* w_ih0 = (const float*)d_in[1];
    const float* w_hh0 = (const float*)d_in[2];
    const float* b_ih0 = (const float*)d_in[3];
    const float* b_hh0 = (const float*)d_in[4];
    const float* w_ih1 = (const float*)d_in[5];
    const float* w_hh1 = (const float*)d_in[6];
    const float* b_ih1 = (const float*)d_in[7];
    const float* b_hh1 = (const float*)d_in[8];
    const float* ew1 = (const float*)d_in[9];
    const float* eb1 = (const float*)d_in[10];
    const float* ew2 = (const float*)d_in[11];
    const float* eb2 = (const float*)d_in[12];
    const float* pw1 = (const float*)d_in[13];
    const float* pb1 = (const float*)d_in[14];
    const float* pw2 = (const float*)d_in[15];
    const float* pb2 = (const float*)d_in[16];
    const float* sw  = (const float*)d_in[17];
    const float* sb  = (const float*)d_in[18];
    float* out = (float*)d_out;
    unsigned char* ws = (unsigned char*)d_ws;   // ~204 KB used

    hipLaunchKernelGGL(prep_kernel, dim3(192), dim3(256), 0, stream,
                       w_ih0, w_hh0, b_ih0, b_hh0, w_ih1, w_hh1, b_ih1, b_hh1, ws);
    hipLaunchKernelGGL(lstm_fused_kernel, dim3(BTOT / BB), dim3(TPB), 0, stream,
                       x, ws, ew1, eb1, ew2, eb2, pw1, pb1, pw2, pb2, sw, sb, out);
}

// Round 5
// 518.305 us; speedup vs baseline: 8.9181x; 1.0836x over previous
//
#include <hip/hip_runtime.h>

typedef __attribute__((ext_vector_type(8))) short short8_t;
typedef __attribute__((ext_vector_type(4))) float f32x4;

#define SEQ  256
#define HID  64
#define FIN  5
#define BB   16
#define TPB  1024
#define BTOT 4096

// ws byte offsets: fragged bf16 weights (hi/lo) + fp32 wih0/biases
#define OFF_W0HI 0
#define OFF_W0LO (32*1024)
#define OFF_W1HI (64*1024)
#define OFF_W1LO (96*1024)
#define OFF_W2HI (128*1024)
#define OFF_W2LO (160*1024)
#define OFF_WIH0 (192*1024)            // 1280 f32: wih0p[c][f]
#define OFF_B0   (192*1024 + 5120)     // 256 f32
#define OFF_B1   (192*1024 + 6144)     // 256 f32

__device__ __forceinline__ float sigf(float v)   { return 1.0f / (1.0f + __expf(-v)); }
__device__ __forceinline__ float tanhf_(float v) { return 2.0f / (1.0f + __expf(-2.0f*v)) - 1.0f; }
__device__ __forceinline__ unsigned short bf16rtn(float v) {
    unsigned int u = __float_as_uint(v);
    u += 0x7fffu + ((u >> 16) & 1u);           // round to nearest even
    return (unsigned short)(u >> 16);
}
__device__ __forceinline__ float bf16tof(unsigned short h) {
    return __uint_as_float(((unsigned int)h) << 16);
}

// ---------------------------------------------------------------------------
// Prep (unchanged from R4): split weights into bf16 hi/lo, pre-fragged for
// mfma_16x16x32: e = ((T*2+ks)*64 + lane)*8 + i, c = 16T + (lane&15),
// k = ks*32 + (lane>>4)*8 + i. Gate-interleaved cols c = 4J + gate.
// ---------------------------------------------------------------------------
__global__ void prep_kernel(const float* __restrict__ wih0, const float* __restrict__ whh0,
                            const float* __restrict__ bih0, const float* __restrict__ bhh0,
                            const float* __restrict__ wih1, const float* __restrict__ whh1,
                            const float* __restrict__ bih1, const float* __restrict__ bhh1,
                            unsigned char* __restrict__ ws) {
    int idx = blockIdx.x * blockDim.x + threadIdx.x;
    if (idx < 3 * 16384) {
        int mat = idx / 16384, e = idx % 16384;
        int tk   = e >> 9;           // T*2+ks, 0..31
        int lane = (e >> 3) & 63;
        int i    = e & 7;
        int c = 16 * (tk >> 1) + (lane & 15);
        int k = (tk & 1) * 32 + (lane >> 4) * 8 + i;
        int row = (c & 3) * 64 + (c >> 2);      // PyTorch row = gate*64 + J
        const float* W = (mat == 0) ? whh0 : (mat == 1) ? whh1 : wih1;
        float v = W[row * HID + k];
        unsigned int vb = __float_as_uint(v);
        unsigned short hi = (unsigned short)(vb >> 16);
        float rem = v - __uint_as_float(vb & 0xffff0000u);
        unsigned short lo = (unsigned short)(__float_as_uint(rem) >> 16);
        int bhiOff = (mat == 0) ? OFF_W0HI : (mat == 1) ? OFF_W1HI : OFF_W2HI;
        int bloOff = (mat == 0) ? OFF_W0LO : (mat == 1) ? OFF_W1LO : OFF_W2LO;
        ((unsigned short*)(ws + bhiOff))[e] = hi;
        ((unsigned short*)(ws + bloOff))[e] = lo;
    }
    if (idx < 1280) {
        int c = idx / FIN, f = idx % FIN;
        int row = (c & 3) * 64 + (c >> 2);
        ((float*)(ws + OFF_WIH0))[idx] = wih0[row * FIN + f];
    }
    if (idx < 256) {
        int row = (idx & 3) * 64 + (idx >> 2);
        ((float*)(ws + OFF_B0))[idx] = bih0[row] + bhh0[row];
        ((float*)(ws + OFF_B1))[idx] = bih1[row] + bhh1[row];
    }
}

// ---------------------------------------------------------------------------
// Fused 2-layer LSTM + heads. 1024 threads = 16 waves; wave w owns gate-col
// tile c in [16w, 16w+16) = hidden units J in [4w, 4w+4), all 4 gates.
// Thread (b=lane&15, g=lane>>4) ends up holding gates (i,f,g,o) of J=4w+g
// for batch b in its 4 D-regs -> pointwise update entirely in registers.
// h-state lives in LDS as ready-made B-fragments (bf16), so reads are
// stride-1 ds_read_b128 (conflict-free) and each wave reads 6 per step.
// ---------------------------------------------------------------------------
__global__ __launch_bounds__(TPB, 4)
void lstm_fused_kernel(const float* __restrict__ x, const unsigned char* __restrict__ ws,
                       const float* __restrict__ ew1, const float* __restrict__ eb1,
                       const float* __restrict__ ew2, const float* __restrict__ eb2,
                       const float* __restrict__ pw1, const float* __restrict__ pb1,
                       const float* __restrict__ pw2, const float* __restrict__ pb2,
                       const float* __restrict__ sw,  const float* __restrict__ sb,
                       float* __restrict__ out) {
    __shared__ unsigned short VS0[2][2][64][8];   // h1 state [buf][ks][lane][elem]
    __shared__ unsigned short VS1[2][2][64][8];   // h2 state
    __shared__ float HS[2][16][17];

    const int tid  = threadIdx.x;
    const int lane = tid & 63;
    const int w    = tid >> 6;      // tile 0..15
    const int b    = lane & 15;     // batch col
    const int g    = lane >> 4;     // k-group / D row-quad
    const int b0g  = blockIdx.x * BB;

    for (int i = tid; i < 2 * 2 * 64 * 8; i += TPB) {
        (&VS0[0][0][0][0])[i] = 0; (&VS1[0][0][0][0])[i] = 0;
    }

    // ---- weight fragments -> VGPRs (once): 12 short8 = 48 VGPR ----
    short8_t A0h[2], A0l[2], A1h[2], A1l[2], A2h[2], A2l[2];
    #pragma unroll
    for (int ks = 0; ks < 2; ++ks) {
        const int fo = ((w * 2 + ks) * 64 + lane) * 16;
        A0h[ks] = *(const short8_t*)(ws + OFF_W0HI + fo);
        A0l[ks] = *(const short8_t*)(ws + OFF_W0LO + fo);
        A1h[ks] = *(const short8_t*)(ws + OFF_W1HI + fo);
        A1l[ks] = *(const short8_t*)(ws + OFF_W1LO + fo);
        A2h[ks] = *(const short8_t*)(ws + OFF_W2HI + fo);
        A2l[ks] = *(const short8_t*)(ws + OFF_W2LO + fo);
    }
    // ---- x-projection weights + biases (fp32, exact) ----
    float wir[4][FIN], bias0r[4], bias1r[4];
    #pragma unroll
    for (int r = 0; r < 4; ++r) {
        const int c = 16 * w + 4 * g + r;
        bias0r[r] = ((const float*)(ws + OFF_B0))[c];
        bias1r[r] = ((const float*)(ws + OFF_B1))[c];
        #pragma unroll
        for (int f = 0; f < FIN; ++f) wir[r][f] = ((const float*)(ws + OFF_WIH0))[c * FIN + f];
    }

    // state write slot: value (J=4w+g, b) -> chunk J>>5, lane' ((J>>3)&3)*16+b, elem J&7
    const int wks = w >> 3, wkg = (w >> 1) & 3, wi = 4 * (w & 1) + g;
    unsigned short* st0 = &VS0[0][wks][wkg * 16 + b][wi];   // buf stride = 1024 elems
    unsigned short* st1 = &VS1[0][wks][wkg * 16 + b][wi];

    const float* xrow = x + (size_t)(b0g + b) * SEQ * FIN;
    float xc[FIN], xn[FIN];
    #pragma unroll
    for (int f = 0; f < FIN; ++f) xc[f] = xrow[f];
    float c1 = 0.f, c2 = 0.f;
    __syncthreads();

#define HALFSTEP(CUR, XU, XP, TP) {                                                 \
    if ((TP) < SEQ) {                                                               \
        _Pragma("unroll") for (int f = 0; f < FIN; ++f) XP[f] = xrow[(TP)*FIN + f]; \
    }                                                                               \
    f32x4 acc;                                                                      \
    _Pragma("unroll") for (int r = 0; r < 4; ++r) {                                 \
        float a = bias0r[r];                                                        \
        _Pragma("unroll") for (int f = 0; f < FIN; ++f) a += XU[f] * wir[r][f];     \
        acc[r] = a;                                                                 \
    }                                                                               \
    _Pragma("unroll") for (int ks = 0; ks < 2; ++ks) {                              \
        short8_t bb = *(const short8_t*)&VS0[CUR][ks][lane][0];                     \
        acc = __builtin_amdgcn_mfma_f32_16x16x32_bf16(A0h[ks], bb, acc, 0, 0, 0);   \
        acc = __builtin_amdgcn_mfma_f32_16x16x32_bf16(A0l[ks], bb, acc, 0, 0, 0);   \
    }                                                                               \
    { float iv = sigf(acc[0]), fv = sigf(acc[1]);                                   \
      float gv = tanhf_(acc[2]), ov = sigf(acc[3]);                                 \
      c1 = fv * c1 + iv * gv;                                                       \
      st0[(CUR ^ 1) * 1024] = bf16rtn(ov * tanhf_(c1)); }                           \
    __syncthreads();                                                                \
    f32x4 d;                                                                        \
    _Pragma("unroll") for (int r = 0; r < 4; ++r) d[r] = bias1r[r];                 \
    _Pragma("unroll") for (int ks = 0; ks < 2; ++ks) {                              \
        short8_t bb = *(const short8_t*)&VS1[CUR][ks][lane][0];                     \
        d = __builtin_amdgcn_mfma_f32_16x16x32_bf16(A1h[ks], bb, d, 0, 0, 0);       \
        d = __builtin_amdgcn_mfma_f32_16x16x32_bf16(A1l[ks], bb, d, 0, 0, 0);       \
    }                                                                               \
    _Pragma("unroll") for (int ks = 0; ks < 2; ++ks) {                              \
        short8_t bb = *(const short8_t*)&VS0[CUR ^ 1][ks][lane][0];                 \
        d = __builtin_amdgcn_mfma_f32_16x16x32_bf16(A2h[ks], bb, d, 0, 0, 0);       \
        d = __builtin_amdgcn_mfma_f32_16x16x32_bf16(A2l[ks], bb, d, 0, 0, 0);       \
    }                                                                               \
    { float iv = sigf(d[0]), fv = sigf(d[1]);                                       \
      float gv = tanhf_(d[2]), ov = sigf(d[3]);                                     \
      c2 = fv * c2 + iv * gv;                                                       \
      st1[(CUR ^ 1) * 1024] = bf16rtn(ov * tanhf_(c2)); }                           \
    __syncthreads(); }

    for (int th = 0; th < SEQ / 2; ++th) {
        HALFSTEP(0, xc, xn, 2 * th + 1)
        HALFSTEP(1, xn, xc, 2 * th + 2)
    }
#undef HALFSTEP

    // ---------------- heads: final h2 in VS1 buffer 0 ----------------
    if (tid < 256) {
        int hb_ = tid >> 4, hi_ = tid & 15;
        float ae = eb1[hi_], ap = pb1[hi_];
        for (int j = 0; j < HID; ++j) {
            float h = bf16tof(VS1[0][j >> 5][((j >> 3) & 3) * 16 + hb_][j & 7]);
            ae += h * ew1[hi_ * HID + j];
            ap += h * pw1[hi_ * HID + j];
        }
        HS[0][hb_][hi_] = fmaxf(ae, 0.0f);
        HS[1][hb_][hi_] = fmaxf(ap, 0.0f);
    }
    if (tid >= 256 && tid < 256 + 80) {
        int t2 = tid - 256, sbb = t2 / 5, ss = t2 % 5;
        float a = sb[ss];
        for (int j = 0; j < HID; ++j)
            a += bf16tof(VS1[0][j >> 5][((j >> 3) & 3) * 16 + sbb][j & 7]) * sw[ss * HID + j];
        out[2 * BTOT + (size_t)(b0g + sbb) * 5 + ss] = a;
    }
    __syncthreads();
    if (tid < BB) {
        float eo = eb2[0], po = pb2[0];
        #pragma unroll
        for (int i2 = 0; i2 < 16; ++i2) {
            eo += HS[0][tid][i2] * ew2[i2];
            po += HS[1][tid][i2] * pw2[i2];
        }
        out[b0g + tid]        = sigf(eo);
        out[BTOT + b0g + tid] = sigf(po);
    }
}

extern "C" void kernel_launch(void* const* d_in, const int* in_sizes, int n_in,
                              void* d_out, int out_size, void* d_ws, size_t ws_size,
                              hipStream_t stream) {
    const float* x     = (const float*)d_in[0];
    const float* w_ih0 = (const float*)d_in[1];
    const float* w_hh0 = (const float*)d_in[2];
    const float* b_ih0 = (const float*)d_in[3];
    const float* b_hh0 = (const float*)d_in[4];
    const float* w_ih1 = (const float*)d_in[5];
    const float* w_hh1 = (const float*)d_in[6];
    const float* b_ih1 = (const float*)d_in[7];
    const float* b_hh1 = (const float*)d_in[8];
    const float* ew1 = (const float*)d_in[9];
    const float* eb1 = (const float*)d_in[10];
    const float* ew2 = (const float*)d_in[11];
    const float* eb2 = (const float*)d_in[12];
    const float* pw1 = (const float*)d_in[13];
    const float* pb1 = (const float*)d_in[14];
    const float* pw2 = (const float*)d_in[15];
    const float* pb2 = (const float*)d_in[16];
    const float* sw  = (const float*)d_in[17];
    const float* sb  = (const float*)d_in[18];
    float* out = (float*)d_out;
    unsigned char* ws = (unsigned char*)d_ws;   // ~204 KB used

    hipLaunchKernelGGL(prep_kernel, dim3(192), dim3(256), 0, stream,
                       w_ih0, w_hh0, b_ih0, b_hh0, w_ih1, w_hh1, b_ih1, b_hh1, ws);
    hipLaunchKernelGGL(lstm_fused_kernel, dim3(BTOT / BB), dim3(TPB), 0, stream,
                       x, ws, ew1, eb1, ew2, eb2, pw1, pb1, pw2, pb2, sw, sb, out);
}

// Round 6
// 409.610 us; speedup vs baseline: 11.2847x; 1.2654x over previous
//
#include <hip/hip_runtime.h>

typedef __attribute__((ext_vector_type(8))) short short8_t;
typedef __attribute__((ext_vector_type(4))) float f32x4;

#define SEQ  256
#define HID  64
#define FIN  5
#define BB   16
#define TPB  1024
#define BTOT 4096

// ws byte offsets
#define OFF_W0HI 0
#define OFF_W0LO (32*1024)
#define OFF_W1HI (64*1024)
#define OFF_W1LO (96*1024)
#define OFF_W2HI (128*1024)
#define OFF_W2LO (160*1024)
#define OFF_WX   (192*1024)     // 16 KB: layer0 x-chunk A-frags (w_ih0 + bias0, hi/lo)
#define OFF_B1   (208*1024)     // 256 f32: gate-interleaved bias1

__device__ __forceinline__ float sigf(float v)   { return 1.0f / (1.0f + __expf(-v)); }
__device__ __forceinline__ float tanhf_(float v) { return 2.0f / (1.0f + __expf(-2.0f*v)) - 1.0f; }
__device__ __forceinline__ unsigned short bf16rtn(float v) {
    unsigned int u = __float_as_uint(v);
    u += 0x7fffu + ((u >> 16) & 1u);
    return (unsigned short)(u >> 16);
}
__device__ __forceinline__ float bf16tof(unsigned short h) {
    return __uint_as_float(((unsigned int)h) << 16);
}

// ---------------------------------------------------------------------------
// Prep: (a) recurrent/input weight matrices split bf16 hi/lo, pre-fragged for
// mfma_16x16x32 (e = ((T*2+ks)*64+lane)*8+i, c = 16T+(lane&15),
// k = ks*32+(lane>>4)*8+i, gate-interleaved cols c=4J+gate);
// (b) x-chunk A-frag: k0-4 w_hi, k5-9 w_hi, k10-14 w_lo, k15 bias_hi,
// k16 bias_lo, rest 0;  (c) bias1 fp32.
// ---------------------------------------------------------------------------
__global__ void prep_kernel(const float* __restrict__ wih0, const float* __restrict__ whh0,
                            const float* __restrict__ bih0, const float* __restrict__ bhh0,
                            const float* __restrict__ wih1, const float* __restrict__ whh1,
                            const float* __restrict__ bih1, const float* __restrict__ bhh1,
                            unsigned char* __restrict__ ws) {
    int idx = blockIdx.x * blockDim.x + threadIdx.x;
    if (idx < 3 * 16384) {
        int mat = idx / 16384, e = idx % 16384;
        int tk   = e >> 9;
        int lane = (e >> 3) & 63;
        int i    = e & 7;
        int c = 16 * (tk >> 1) + (lane & 15);
        int k = (tk & 1) * 32 + (lane >> 4) * 8 + i;
        int row = (c & 3) * 64 + (c >> 2);
        const float* W = (mat == 0) ? whh0 : (mat == 1) ? whh1 : wih1;
        float v = W[row * HID + k];
        unsigned int vb = __float_as_uint(v);
        unsigned short hi = (unsigned short)(vb >> 16);
        float rem = v - __uint_as_float(vb & 0xffff0000u);
        unsigned short lo = bf16rtn(rem);
        int bhiOff = (mat == 0) ? OFF_W0HI : (mat == 1) ? OFF_W1HI : OFF_W2HI;
        int bloOff = (mat == 0) ? OFF_W0LO : (mat == 1) ? OFF_W1LO : OFF_W2LO;
        ((unsigned short*)(ws + bhiOff))[e] = hi;
        ((unsigned short*)(ws + bloOff))[e] = lo;
    } else if (idx < 3 * 16384 + 8192) {
        int e = idx - 3 * 16384;
        int w = e >> 9, r2 = e & 511;
        int lane = r2 >> 3, i = r2 & 7;
        int c = 16 * w + (lane & 15);
        int k = (lane >> 4) * 8 + i;
        int row = (c & 3) * 64 + (c >> 2);
        unsigned short outv = 0;
        if (k < 15) {
            float v = wih0[row * FIN + (k % 5)];
            unsigned int vb = __float_as_uint(v);
            if (k < 10) outv = (unsigned short)(vb >> 16);
            else        outv = bf16rtn(v - __uint_as_float(vb & 0xffff0000u));
        } else if (k == 15 || k == 16) {
            float bv = bih0[row] + bhh0[row];
            unsigned int vb = __float_as_uint(bv);
            if (k == 15) outv = (unsigned short)(vb >> 16);
            else         outv = bf16rtn(bv - __uint_as_float(vb & 0xffff0000u));
        }
        ((unsigned short*)(ws + OFF_WX))[e] = outv;
    }
    if (idx < 256) {
        int row = (idx & 3) * 64 + (idx >> 2);
        ((float*)(ws + OFF_B1))[idx] = bih1[idx && false ? 0 : row] + bhh1[row];
    }
}

// ---------------------------------------------------------------------------
// Fused 2-layer LSTM + heads. 1024 threads = 16 waves; wave w owns gate-cols
// [16w,16w+16) = hidden units J in [4w,4w+4). Thread (b=lane&15, g=lane>>4)
// holds gates (i,f,g,o) of J=4w+g for batch b -> pointwise update in regs.
// States are ready-made MFMA B-frags in LDS (stride-1 ds_read_b128).
// x enters layer0 as a 3rd K-chunk (XF frag built by 16 writer threads).
// ONE barrier per timestep (double-buffered states).
// ---------------------------------------------------------------------------
__global__ __launch_bounds__(TPB, 4)
void lstm_fused_kernel(const float* __restrict__ x, const unsigned char* __restrict__ ws,
                       const float* __restrict__ ew1, const float* __restrict__ eb1,
                       const float* __restrict__ ew2, const float* __restrict__ eb2,
                       const float* __restrict__ pw1, const float* __restrict__ pb1,
                       const float* __restrict__ pw2, const float* __restrict__ pb2,
                       const float* __restrict__ sw,  const float* __restrict__ sb,
                       float* __restrict__ out) {
    __shared__ __attribute__((aligned(16))) unsigned short VS0[2][2][64][8];
    __shared__ __attribute__((aligned(16))) unsigned short VS1[2][2][64][8];
    __shared__ __attribute__((aligned(16))) unsigned short XF[2][64][8];
    __shared__ float HS[2][16][17];

    const int tid  = threadIdx.x;
    const int lane = tid & 63;
    const int w    = tid >> 6;
    const int b    = lane & 15;
    const int g    = lane >> 4;
    const int b0g  = blockIdx.x * BB;
    const bool iswr = (tid < 16);

    for (int i = tid; i < 2 * 2 * 64 * 8; i += TPB) {
        (&VS0[0][0][0][0])[i] = 0; (&VS1[0][0][0][0])[i] = 0;
    }
    for (int i = tid; i < 2 * 64 * 8; i += TPB) (&XF[0][0][0])[i] = 0;

    // ---- weight fragments -> registers (once): 13 short8 ----
    short8_t A0h[2], A0l[2], A1h[2], A1l[2], A2h[2], A2l[2], AX;
    #pragma unroll
    for (int ks = 0; ks < 2; ++ks) {
        const int fo = ((w * 2 + ks) * 64 + lane) * 16;
        A0h[ks] = *(const short8_t*)(ws + OFF_W0HI + fo);
        A0l[ks] = *(const short8_t*)(ws + OFF_W0LO + fo);
        A1h[ks] = *(const short8_t*)(ws + OFF_W1HI + fo);
        A1l[ks] = *(const short8_t*)(ws + OFF_W1LO + fo);
        A2h[ks] = *(const short8_t*)(ws + OFF_W2HI + fo);
        A2l[ks] = *(const short8_t*)(ws + OFF_W2LO + fo);
    }
    AX = *(const short8_t*)(ws + OFF_WX + (w * 64 + lane) * 16);
    float bias1r[4];
    #pragma unroll
    for (int r = 0; r < 4; ++r)
        bias1r[r] = ((const float*)(ws + OFF_B1))[16 * w + 4 * g + r];

    // state write slot for value (J=4w+g, b)
    const int wks = w >> 3, wkg = (w >> 1) & 3, wi = 4 * (w & 1) + g;
    unsigned short* st0 = &VS0[0][wks][wkg * 16 + b][wi];   // buf stride 1024
    unsigned short* st1 = &VS1[0][wks][wkg * 16 + b][wi];

    const float* xrow = x + (size_t)(b0g + b) * (SEQ * FIN);
    float c1 = 0.f, c2 = 0.f;

    // writer: build XF frag for x_t into XF[BUF]; k0-4 xhi, 5-9 xlo, 10-14 xhi,
    // 15,16 = 1.0 (chunk1 word3 hi + chunk2 word0 lo). Chunks 2,3 const.
#define BUILD_XF(BUF, T) {                                                         \
    const float* xp = xrow + (T) * FIN;                                            \
    float v0 = xp[0], v1 = xp[1], v2 = xp[2], v3 = xp[3], v4 = xp[4];              \
    unsigned int u0 = __float_as_uint(v0), u1 = __float_as_uint(v1),               \
                 u2 = __float_as_uint(v2), u3 = __float_as_uint(v3),               \
                 u4 = __float_as_uint(v4);                                         \
    unsigned int h0 = u0 >> 16, h1 = u1 >> 16, h2 = u2 >> 16, h3 = u3 >> 16, h4 = u4 >> 16; \
    unsigned int l0 = bf16rtn(v0 - __uint_as_float(u0 & 0xffff0000u));             \
    unsigned int l1 = bf16rtn(v1 - __uint_as_float(u1 & 0xffff0000u));             \
    unsigned int l2 = bf16rtn(v2 - __uint_as_float(u2 & 0xffff0000u));             \
    unsigned int l3 = bf16rtn(v3 - __uint_as_float(u3 & 0xffff0000u));             \
    unsigned int l4 = bf16rtn(v4 - __uint_as_float(u4 & 0xffff0000u));             \
    uint4 ch0, ch1;                                                                \
    ch0.x = h0 | (h1 << 16); ch0.y = h2 | (h3 << 16);                              \
    ch0.z = h4 | (l0 << 16); ch0.w = l1 | (l2 << 16);                              \
    ch1.x = l3 | (l4 << 16); ch1.y = h0 | (h1 << 16);                              \
    ch1.z = h2 | (h3 << 16); ch1.w = h4 | (0x3F80u << 16);                         \
    *(uint4*)&XF[BUF][0 * 16 + tid][0] = ch0;                                      \
    *(uint4*)&XF[BUF][1 * 16 + tid][0] = ch1;                                      \
}

    if (iswr) {
        XF[0][2 * 16 + tid][0] = 0x3F80;    // k16 = 1.0, both buffers (const)
        XF[1][2 * 16 + tid][0] = 0x3F80;
        BUILD_XF(0, 0)
    }
    __syncthreads();

#define STEP(CUR, TP) {                                                                 \
    /* ---- layer 0: gates = [Wx|bias]*xfrag + W0*h1prev ---- */                        \
    f32x4 accA = {0.f, 0.f, 0.f, 0.f};                                                  \
    f32x4 accB = {0.f, 0.f, 0.f, 0.f};                                                  \
    {                                                                                   \
        short8_t xf = *(const short8_t*)&XF[CUR][lane][0];                              \
        short8_t s0 = *(const short8_t*)&VS0[CUR][0][lane][0];                          \
        short8_t s1 = *(const short8_t*)&VS0[CUR][1][lane][0];                          \
        accA = __builtin_amdgcn_mfma_f32_16x16x32_bf16(AX,     xf, accA, 0, 0, 0);      \
        accB = __builtin_amdgcn_mfma_f32_16x16x32_bf16(A0h[1], s1, accB, 0, 0, 0);      \
        accA = __builtin_amdgcn_mfma_f32_16x16x32_bf16(A0h[0], s0, accA, 0, 0, 0);      \
        accB = __builtin_amdgcn_mfma_f32_16x16x32_bf16(A0l[1], s1, accB, 0, 0, 0);      \
        accA = __builtin_amdgcn_mfma_f32_16x16x32_bf16(A0l[0], s0, accA, 0, 0, 0);      \
    }                                                                                   \
    accA[0] += accB[0]; accA[1] += accB[1]; accA[2] += accB[2]; accA[3] += accB[3];     \
    {                                                                                   \
        float iv = sigf(accA[0]), fv = sigf(accA[1]);                                   \
        float gv = tanhf_(accA[2]), ov = sigf(accA[3]);                                 \
        c1 = fv * c1 + iv * gv;                                                         \
        st0[(CUR ^ 1) * 1024] = bf16rtn(ov * tanhf_(c1));                               \
    }                                                                                   \
    if (iswr && (TP) < SEQ) BUILD_XF(CUR ^ 1, TP)                                       \
    __syncthreads();                                                                    \
    /* ---- layer 1: gates = bias1 + W1*h2prev + W2*h1cur ---- */                       \
    f32x4 dA, dB = {0.f, 0.f, 0.f, 0.f};                                                \
    dA[0] = bias1r[0]; dA[1] = bias1r[1]; dA[2] = bias1r[2]; dA[3] = bias1r[3];         \
    {                                                                                   \
        short8_t h20 = *(const short8_t*)&VS1[CUR][0][lane][0];                         \
        short8_t h21 = *(const short8_t*)&VS1[CUR][1][lane][0];                         \
        short8_t h10 = *(const short8_t*)&VS0[CUR ^ 1][0][lane][0];                     \
        short8_t h11 = *(const short8_t*)&VS0[CUR ^ 1][1][lane][0];                     \
        dA = __builtin_amdgcn_mfma_f32_16x16x32_bf16(A1h[0], h20, dA, 0, 0, 0);         \
        dB = __builtin_amdgcn_mfma_f32_16x16x32_bf16(A1h[1], h21, dB, 0, 0, 0);         \
        dA = __builtin_amdgcn_mfma_f32_16x16x32_bf16(A1l[0], h20, dA, 0, 0, 0);         \
        dB = __builtin_amdgcn_mfma_f32_16x16x32_bf16(A1l[1], h21, dB, 0, 0, 0);         \
        dA = __builtin_amdgcn_mfma_f32_16x16x32_bf16(A2h[0], h10, dA, 0, 0, 0);         \
        dB = __builtin_amdgcn_mfma_f32_16x16x32_bf16(A2h[1], h11, dB, 0, 0, 0);         \
        dA = __builtin_amdgcn_mfma_f32_16x16x32_bf16(A2l[0], h10, dA, 0, 0, 0);         \
        dB = __builtin_amdgcn_mfma_f32_16x16x32_bf16(A2l[1], h11, dB, 0, 0, 0);         \
    }                                                                                   \
    dA[0] += dB[0]; dA[1] += dB[1]; dA[2] += dB[2]; dA[3] += dB[3];                     \
    {                                                                                   \
        float iv = sigf(dA[0]), fv = sigf(dA[1]);                                       \
        float gv = tanhf_(dA[2]), ov = sigf(dA[3]);                                     \
        c2 = fv * c2 + iv * gv;                                                         \
        st1[(CUR ^ 1) * 1024] = bf16rtn(ov * tanhf_(c2));                               \
    }                                                                                   \
}

    for (int th = 0; th < SEQ / 2; ++th) {
        STEP(0, 2 * th + 1)
        STEP(1, 2 * th + 2)
    }
#undef STEP
#undef BUILD_XF

    __syncthreads();
    // ---------------- heads: final h2 in VS1 buffer 0 ----------------
    if (tid < 256) {
        int hb_ = tid >> 4, hi_ = tid & 15;
        float ae = eb1[hi_], ap = pb1[hi_];
        for (int j = 0; j < HID; ++j) {
            float h = bf16tof(VS1[0][j >> 5][((j >> 3) & 3) * 16 + hb_][j & 7]);
            ae += h * ew1[hi_ * HID + j];
            ap += h * pw1[hi_ * HID + j];
        }
        HS[0][hb_][hi_] = fmaxf(ae, 0.0f);
        HS[1][hb_][hi_] = fmaxf(ap, 0.0f);
    }
    if (tid >= 256 && tid < 256 + 80) {
        int t2 = tid - 256, sbb = t2 / 5, ss = t2 % 5;
        float a = sb[ss];
        for (int j = 0; j < HID; ++j)
            a += bf16tof(VS1[0][j >> 5][((j >> 3) & 3) * 16 + sbb][j & 7]) * sw[ss * HID + j];
        out[2 * BTOT + (size_t)(b0g + sbb) * 5 + ss] = a;
    }
    __syncthreads();
    if (tid < BB) {
        float eo = eb2[0], po = pb2[0];
        #pragma unroll
        for (int i2 = 0; i2 < 16; ++i2) {
            eo += HS[0][tid][i2] * ew2[i2];
            po += HS[1][tid][i2] * pw2[i2];
        }
        out[b0g + tid]        = sigf(eo);
        out[BTOT + b0g + tid] = sigf(po);
    }
}

extern "C" void kernel_launch(void* const* d_in, const int* in_sizes, int n_in,
                              void* d_out, int out_size, void* d_ws, size_t ws_size,
                              hipStream_t stream) {
    const float* x     = (const float*)d_in[0];
    const float* w_ih0 = (const float*)d_in[1];
    const float* w_hh0 = (const float*)d_in[2];
    const float* b_ih0 = (const float*)d_in[3];
    const float* b_hh0 = (const float*)d_in[4];
    const float* w_ih1 = (const float*)d_in[5];
    const float* w_hh1 = (const float*)d_in[6];
    const float* b_ih1 = (const float*)d_in[7];
    const float* b_hh1 = (const float*)d_in[8];
    const float* ew1 = (const float*)d_in[9];
    const float* eb1 = (const float*)d_in[10];
    const float* ew2 = (const float*)d_in[11];
    const float* eb2 = (const float*)d_in[12];
    const float* pw1 = (const float*)d_in[13];
    const float* pb1 = (const float*)d_in[14];
    const float* pw2 = (const float*)d_in[15];
    const float* pb2 = (const float*)d_in[16];
    const float* sw  = (const float*)d_in[17];
    const float* sb  = (const float*)d_in[18];
    float* out = (float*)d_out;
    unsigned char* ws = (unsigned char*)d_ws;   // ~209 KB used

    hipLaunchKernelGGL(prep_kernel, dim3(224), dim3(256), 0, stream,
                       w_ih0, w_hh0, b_ih0, b_hh0, w_ih1, w_hh1, b_ih1, b_hh1, ws);
    hipLaunchKernelGGL(lstm_fused_kernel, dim3(BTOT / BB), dim3(TPB), 0, stream,
                       x, ws, ew1, eb1, ew2, eb2, pw1, pb1, pw2, pb2, sw, sb, out);
}